// Round 7
// baseline (367.842 us; speedup 1.0000x reference)
//
#include <hip/hip_runtime.h>
#include <hip/hip_bf16.h>
#include <math.h>

typedef __attribute__((ext_vector_type(8))) short bf16x8;
typedef __attribute__((ext_vector_type(4))) short short4v;
typedef __attribute__((ext_vector_type(4))) float f32x4;
typedef __attribute__((ext_vector_type(16))) float f32x16;

#define MFMA16(a,b,c) __builtin_amdgcn_mfma_f32_16x16x32_bf16(a,b,c,0,0,0)
#define MFMA32(a,b,c) __builtin_amdgcn_mfma_f32_32x32x16_bf16(a,b,c,0,0,0)

__device__ __forceinline__ unsigned short f2bf(float f) {
  union { float f; unsigned u; } v; v.f = f;
  unsigned r = v.u + 0x7FFFu + ((v.u >> 16) & 1u);
  return (unsigned short)(r >> 16);
}

__device__ __forceinline__ unsigned cvt_pk(float lo, float hi) {
  unsigned r;
  asm("v_cvt_pk_bf16_f32 %0, %1, %2" : "=v"(r) : "v"(lo), "v"(hi));
  return r;
}

__device__ __forceinline__ void async_load16(const void* g, void* lds) {
  __builtin_amdgcn_global_load_lds(
      (const __attribute__((address_space(1))) unsigned int*)g,
      (__attribute__((address_space(3))) unsigned int*)lds, 16, 0, 0);
}

__device__ __forceinline__ f32x16 zero16() {
  f32x16 z;
#pragma unroll
  for (int i = 0; i < 16; ++i) z[i] = 0.f;
  return z;
}

// ---------------- RoPE table ----------------
__global__ void rope_table_kernel(float* __restrict__ tc, float* __restrict__ ts) {
  int i = blockIdx.x * 256 + threadIdx.x;
  if (i >= 2048 * 32) return;
  int s = i >> 5, j = i & 31;
  double invf = pow(10000.0, -(double)(2 * j) / 64.0);
  double ang = (double)s * invf;
  tc[i] = (float)cos(ang);
  ts[i] = (float)sin(ang);
}

// ---------------- fp32 -> bf16 elementwise ----------------
__global__ __launch_bounds__(256) void cvt_kernel(const float* __restrict__ in,
                                                  unsigned short* __restrict__ out, int n4) {
  int i = blockIdx.x * 256 + threadIdx.x;
  if (i >= n4) return;
  float4 v = ((const float4*)in)[i];
  short4v o;
  o[0] = (short)f2bf(v.x); o[1] = (short)f2bf(v.y);
  o[2] = (short)f2bf(v.z); o[3] = (short)f2bf(v.w);
  *(short4v*)&out[(size_t)i * 4] = o;
}

// ---------------- fp32 [R][C] -> bf16 [C][R] transpose ----------------
__global__ __launch_bounds__(256) void transpose_cvt(const float* __restrict__ in,
                                                     unsigned short* __restrict__ out,
                                                     int R, int C) {
  __shared__ float tile[32][33];
  const int bx = blockIdx.x * 32, by = blockIdx.y * 32;
  const int tx = threadIdx.x & 31, ty0 = threadIdx.x >> 5;
#pragma unroll
  for (int p = 0; p < 4; ++p) {
    int r = ty0 + p * 8;
    tile[r][tx] = in[(size_t)(by + r) * C + bx + tx];
  }
  __syncthreads();
#pragma unroll
  for (int p = 0; p < 4; ++p) {
    int r = ty0 + p * 8;
    out[(size_t)(bx + r) * R + by + tx] = f2bf(tile[tx][r]);
  }
}

// ---------------- GEMM (m97 structure) ----------------
__global__ __launch_bounds__(256) void gemm_bt(const unsigned short* __restrict__ A,
                                               const unsigned short* __restrict__ Bt,
                                               float* __restrict__ C,
                                               int M, int N, int K) {
  __shared__ unsigned short As[128 * 32];
  __shared__ unsigned short Bs[128 * 32];
  const int t = threadIdx.x, lane = t & 63, wv = t >> 6;
  const int bn = blockIdx.x, bm = blockIdx.y;
  const int m0 = bm * 128, n0 = bn * 128;
  f32x4 acc[4][4];
#pragma unroll
  for (int m = 0; m < 4; ++m)
#pragma unroll
    for (int n = 0; n < 4; ++n) acc[m][n] = (f32x4){0.f, 0.f, 0.f, 0.f};
  const int wr = (wv >> 1) * 64, wc = (wv & 1) * 64;
  const int ar = lane & 15, ak = (lane >> 4) * 8;
  const int srow = lane >> 2, skc = (lane & 3) * 8;
  const int nkt = K >> 5;
  for (int kt = 0; kt < nkt; ++kt) {
    const unsigned short* Ag = A + (size_t)m0 * K + kt * 32;
    const unsigned short* Bg = Bt + (size_t)n0 * K + kt * 32;
#pragma unroll
    for (int p = 0; p < 2; ++p) {
      int c = wv * 2 + p;
      async_load16(Ag + (size_t)(c * 16 + srow) * K + skc, &As[c * 512]);
      async_load16(Bg + (size_t)(c * 16 + srow) * K + skc, &Bs[c * 512]);
    }
    __syncthreads();
    bf16x8 af[4], bfr[4];
#pragma unroll
    for (int m = 0; m < 4; ++m) af[m] = *(const bf16x8*)&As[(wr + m * 16 + ar) * 32 + ak];
#pragma unroll
    for (int n = 0; n < 4; ++n) bfr[n] = *(const bf16x8*)&Bs[(wc + n * 16 + ar) * 32 + ak];
#pragma unroll
    for (int m = 0; m < 4; ++m)
#pragma unroll
      for (int n = 0; n < 4; ++n) acc[m][n] = MFMA16(af[m], bfr[n], acc[m][n]);
    __syncthreads();
  }
#pragma unroll
  for (int m = 0; m < 4; ++m) {
    int row = m0 + wr + m * 16 + (lane >> 4) * 4;
#pragma unroll
    for (int n = 0; n < 4; ++n) {
      int col = n0 + wc + n * 16 + ar;
      float* cp = C + (size_t)row * N + col;
#pragma unroll
      for (int j = 0; j < 4; ++j) cp[(size_t)j * N] = acc[m][n][j];
    }
  }
}

// ---------------- RoPE apply + head split + V transpose ----------------
// Q gets 0.125 * log2(e) prescale (softmax runs in exp2 domain).
__global__ __launch_bounds__(256) void rope_kernel(const float* __restrict__ qkv,
                                                   const float* __restrict__ tc,
                                                   const float* __restrict__ ts,
                                                   unsigned short* __restrict__ qo,
                                                   unsigned short* __restrict__ ko,
                                                   unsigned short* __restrict__ vt) {
  const int S = 2048;
  const int bx = blockIdx.x;
  const int st = bx & 31, bh = bx >> 5;
  const int b = bh >> 4, h = bh & 15;
  const int t = threadIdx.x;
  const int sl = t >> 2, j0 = (t & 3) * 8;
  const int s = st * 64 + sl;
  const float* row = qkv + (size_t)(b * S + s) * 3072;
  float cv[8], sv[8];
#pragma unroll
  for (int i = 0; i < 8; ++i) {
    cv[i] = tc[s * 32 + j0 + i];
    sv[i] = ts[s * 32 + j0 + i];
  }
  __shared__ unsigned short vtile[64][66];
#pragma unroll
  for (int m = 0; m < 2; ++m) {
    const int col0 = m * 1024 + h * 64;
    const float qscale = (m == 0) ? 0.125f * 1.44269504088896340736f : 1.0f;
    float lo[8], hi[8];
#pragma unroll
    for (int i = 0; i < 8; ++i) {
      lo[i] = row[col0 + j0 + i];
      hi[i] = row[col0 + 32 + j0 + i];
    }
    bf16x8 outlo, outhi;
#pragma unroll
    for (int i = 0; i < 8; ++i) {
      outlo[i] = (short)f2bf((lo[i] * cv[i] - hi[i] * sv[i]) * qscale);
      outhi[i] = (short)f2bf((hi[i] * cv[i] + lo[i] * sv[i]) * qscale);
    }
    unsigned short* dst = (m == 0 ? qo : ko) + (size_t)(bh * S + s) * 64;
    *(bf16x8*)&dst[j0] = outlo;
    *(bf16x8*)&dst[32 + j0] = outhi;
  }
  {
    const int col0 = 2048 + h * 64;
#pragma unroll
    for (int i = 0; i < 8; ++i) {
      vtile[j0 + i][sl] = f2bf(row[col0 + j0 + i]);
      vtile[j0 + 32 + i][sl] = f2bf(row[col0 + 32 + j0 + i]);
    }
  }
  __syncthreads();
  {
    const int hd = t >> 2, sc0 = (t & 3) * 16;
    unsigned short* dst = vt + ((size_t)bh * 64 + hd) * S + st * 64 + sc0;
    bf16x8 a, bv;
#pragma unroll
    for (int i = 0; i < 8; ++i) {
      a[i] = (short)vtile[hd][sc0 + i];
      bv[i] = (short)vtile[hd][sc0 + 8 + i];
    }
    *(bf16x8*)&dst[0] = a;
    *(bf16x8*)&dst[8] = bv;
  }
}

// ---------------- attention: single-chain waves, 4 blocks/CU ----------------
// R5's proven per-tile math, one q-group (32 rows) per wave. 1024 blocks ->
// 4 blocks/CU -> 4 waves/SIMD TLP to hide the per-tile dependency chain.

__device__ __forceinline__ bf16x8 buildP(const unsigned* w, int tt, int hi) {
  const int base = (tt & 1) * 4 + (tt >> 1) * 8;
  unsigned wA = w[base], wB = w[base + 1], wC = w[base + 2], wD = w[base + 3];
  unsigned s1v = __shfl_xor(hi ? wA : wC, 32);
  unsigned s2v = __shfl_xor(hi ? wB : wD, 32);
  union { unsigned u[4]; bf16x8 v; } pw;
  pw.u[0] = hi ? s1v : wA;
  pw.u[1] = hi ? s2v : wB;
  pw.u[2] = hi ? wC : s1v;
  pw.u[3] = hi ? wD : s2v;
  return pw.v;
}

// softmax update. l_run holds per-lane half-sums (combined at epilogue).
template<int BANKS>
__device__ __forceinline__ void softmax_chain(f32x16& s0, f32x16& s1,
                                              float& m_run, float& l_run,
                                              f32x16& a0, f32x16& a1, unsigned* w) {
  float p[8];
#pragma unroll
  for (int i = 0; i < 8; ++i) p[i] = fmaxf(s0[2 * i], s0[2 * i + 1]);
  if (BANKS == 2) {
#pragma unroll
    for (int i = 0; i < 8; ++i) p[i] = fmaxf(p[i], fmaxf(s1[2 * i], s1[2 * i + 1]));
  }
#pragma unroll
  for (int i = 0; i < 4; ++i) p[i] = fmaxf(p[i], p[i + 4]);
  float mx = fmaxf(fmaxf(p[0], p[1]), fmaxf(p[2], p[3]));
  mx = fmaxf(mx, __shfl_xor(mx, 32));
  const bool defer = __all(mx - m_run <= 8.0f) != 0;
  const float mn = defer ? m_run : fmaxf(m_run, mx);
  float r0 = 0.f, r1 = 0.f, r2 = 0.f, r3 = 0.f;
#pragma unroll
  for (int i = 0; i < 4; ++i) {
    float e0 = exp2f(s0[4 * i + 0] - mn); s0[4 * i + 0] = e0; r0 += e0;
    float e1 = exp2f(s0[4 * i + 1] - mn); s0[4 * i + 1] = e1; r1 += e1;
    float e2 = exp2f(s0[4 * i + 2] - mn); s0[4 * i + 2] = e2; r2 += e2;
    float e3 = exp2f(s0[4 * i + 3] - mn); s0[4 * i + 3] = e3; r3 += e3;
  }
  if (BANKS == 2) {
#pragma unroll
    for (int i = 0; i < 4; ++i) {
      float e0 = exp2f(s1[4 * i + 0] - mn); s1[4 * i + 0] = e0; r0 += e0;
      float e1 = exp2f(s1[4 * i + 1] - mn); s1[4 * i + 1] = e1; r1 += e1;
      float e2 = exp2f(s1[4 * i + 2] - mn); s1[4 * i + 2] = e2; r2 += e2;
      float e3 = exp2f(s1[4 * i + 3] - mn); s1[4 * i + 3] = e3; r3 += e3;
    }
  }
  const float rs = (r0 + r1) + (r2 + r3);
  if (defer) {
    l_run += rs;
  } else {
    const float scl = exp2f(m_run - mn);
    m_run = mn;
    l_run = l_run * scl + rs;
#pragma unroll
    for (int r = 0; r < 16; ++r) { a0[r] *= scl; a1[r] *= scl; }
  }
#pragma unroll
  for (int i = 0; i < 8; ++i) w[i] = cvt_pk(s0[2 * i], s0[2 * i + 1]);
  if (BANKS == 2) {
#pragma unroll
    for (int i = 0; i < 8; ++i) w[8 + i] = cvt_pk(s1[2 * i], s1[2 * i + 1]);
  }
}

// MODE: 0=full, 1=diag even-g (bank1 dead), 2=diag odd-g (bank1 masked)
template<int MODE>
__device__ __forceinline__ void tile_one(
    const unsigned short* __restrict__ kb, const unsigned short* __restrict__ vb,
    int ql, int hi,
    const bf16x8 (&qf)[4], f32x16& a0, f32x16& a1, float& m_run, float& l_run) {
  constexpr bool b1 = (MODE != 1);
  constexpr int NT = b1 ? 4 : 2;
  const int S = 2048;

  bf16x8 k0[4], k1[4];
#pragma unroll
  for (int s = 0; s < 4; ++s) {
    k0[s] = *(const bf16x8*)&kb[ql * 64 + s * 16 + hi * 8];
    if (b1) k1[s] = *(const bf16x8*)&kb[(32 + ql) * 64 + s * 16 + hi * 8];
  }
  // V issued early; consumed after QK+softmax -> latency hidden
  bf16x8 v0[4], v1[4];
#pragma unroll
  for (int tt = 0; tt < NT; ++tt) {
    v0[tt] = *(const bf16x8*)&vb[(size_t)ql * S + tt * 16 + hi * 8];
    v1[tt] = *(const bf16x8*)&vb[(size_t)(32 + ql) * S + tt * 16 + hi * 8];
  }

  f32x16 s0 = zero16(), s1;
  if (b1) s1 = zero16();
  __builtin_amdgcn_s_setprio(1);
#pragma unroll
  for (int s = 0; s < 4; ++s) {
    s0 = MFMA32(k0[s], qf[s], s0);
    if (b1) s1 = MFMA32(k1[s], qf[s], s1);
  }
  __builtin_amdgcn_s_setprio(0);

  if (MODE == 1) {
#pragma unroll
    for (int r = 0; r < 16; ++r) {
      const int key = (r & 3) + 8 * (r >> 2) + 4 * hi;
      if (key > ql) s0[r] = -INFINITY;
    }
  }
  if (MODE == 2) {
#pragma unroll
    for (int r = 0; r < 16; ++r) {
      const int key = (r & 3) + 8 * (r >> 2) + 4 * hi;
      if (key > ql) s1[r] = -INFINITY;
    }
  }

  unsigned w[16];
  softmax_chain<b1 ? 2 : 1>(s0, s1, m_run, l_run, a0, a1, w);

  __builtin_amdgcn_s_setprio(1);
#pragma unroll
  for (int tt = 0; tt < NT; ++tt) {
    bf16x8 p = buildP(w, tt, hi);
    a0 = MFMA32(v0[tt], p, a0);
    a1 = MFMA32(v1[tt], p, a1);
  }
  __builtin_amdgcn_s_setprio(0);
}

// grid: 1024 blocks (XCD-swizzled, 8 chunks of 128 = 8 bh x 16 i per XCD).
// Block (bh, i): 4 waves take groups {i, 31-i, 32+i, 63-i} rotated by (wv+i)&3
// -> block total exactly 66 tiles; rotation mixes chain lengths across SIMDs.
__global__ __launch_bounds__(256, 4) void attn_kernel(const unsigned short* __restrict__ Q,
                                                      const unsigned short* __restrict__ Kk,
                                                      const unsigned short* __restrict__ Vt,
                                                      unsigned short* __restrict__ O) {
  const int S = 2048;
  const int t = threadIdx.x, lane = t & 63, wv = t >> 6;
  const int swz = (blockIdx.x & 7) * 128 + (blockIdx.x >> 3);
  const int bh = swz >> 4, i = swz & 15;
  const int b = bh >> 4, h = bh & 15;
  const int sel = (wv + i) & 3;
  const int g = (sel == 0) ? i : (sel == 1) ? 31 - i : (sel == 2) ? 32 + i : 63 - i;
  const int kd = g >> 1;
  const int ql = lane & 31, hi = lane >> 5;
  const unsigned short* qh = Q + (size_t)bh * S * 64;
  const unsigned short* kh = Kk + (size_t)bh * S * 64;
  const unsigned short* vh = Vt + (size_t)bh * 64 * S;

  bf16x8 qf[4];
#pragma unroll
  for (int s = 0; s < 4; ++s)
    qf[s] = *(const bf16x8*)&qh[(size_t)(32 * g + ql) * 64 + s * 16 + hi * 8];

  f32x16 a0 = zero16(), a1 = zero16();
  float m_run = -INFINITY, l_run = 0.f;

  for (int kt = 0; kt < kd; ++kt)
    tile_one<0>(kh + (size_t)kt * 4096, vh + kt * 64, ql, hi, qf, a0, a1, m_run, l_run);
  if (g & 1)
    tile_one<2>(kh + (size_t)kd * 4096, vh + kd * 64, ql, hi, qf, a0, a1, m_run, l_run);
  else
    tile_one<1>(kh + (size_t)kd * 4096, vh + kd * 64, ql, hi, qf, a0, a1, m_run, l_run);

  l_run += __shfl_xor(l_run, 32);
  const float inv = 1.f / l_run;
  unsigned short* orow = O + (size_t)(b * S + 32 * g + ql) * 1024 + h * 64;
#pragma unroll
  for (int r = 0; r < 16; ++r) {
    int d = (r & 3) + 8 * (r >> 2) + 4 * hi;
    orow[d] = f2bf(a0[r] * inv);
    orow[32 + d] = f2bf(a1[r] * inv);
  }
}

extern "C" void kernel_launch(void* const* d_in, const int* in_sizes, int n_in,
                              void* d_out, int out_size, void* d_ws, size_t ws_size,
                              hipStream_t stream) {
  const float* x = (const float*)d_in[0];
  const float* Wqkv = (const float*)d_in[1];
  const float* Wout = (const float*)d_in[2];
  float* out = (float*)d_out;

  char* ws = (char*)d_ws;
  size_t off = 0;
  auto take = [&](size_t bytes) {
    void* p = ws + off;
    off += (bytes + 255) & ~(size_t)255;
    return p;
  };
  float* tc = (float*)take(2048 * 32 * 4);
  float* tsn = (float*)take(2048 * 32 * 4);
  unsigned short* xbf = (unsigned short*)take((size_t)8192 * 1024 * 2);
  unsigned short* wqkvT = (unsigned short*)take((size_t)3072 * 1024 * 2);
  unsigned short* woutT = (unsigned short*)take((size_t)1024 * 1024 * 2);
  float* qkvf = (float*)take((size_t)8192 * 3072 * 4);
  unsigned short* qb_ = (unsigned short*)take((size_t)64 * 2048 * 64 * 2);
  unsigned short* kb_ = (unsigned short*)take((size_t)64 * 2048 * 64 * 2);
  unsigned short* vt = (unsigned short*)take((size_t)64 * 64 * 2048 * 2);
  unsigned short* attn = (unsigned short*)take((size_t)8192 * 1024 * 2);

  rope_table_kernel<<<256, 256, 0, stream>>>(tc, tsn);
  cvt_kernel<<<(2097152 + 255) / 256, 256, 0, stream>>>(x, xbf, 2097152);
  {
    dim3 g(96, 32);
    transpose_cvt<<<g, 256, 0, stream>>>(Wqkv, wqkvT, 1024, 3072);
  }
  {
    dim3 g(32, 32);
    transpose_cvt<<<g, 256, 0, stream>>>(Wout, woutT, 1024, 1024);
  }
  {
    dim3 g(24, 64);
    gemm_bt<<<g, 256, 0, stream>>>(xbf, wqkvT, qkvf, 8192, 3072, 1024);
  }
  rope_kernel<<<2048, 256, 0, stream>>>(qkvf, tc, tsn, qb_, kb_, vt);
  attn_kernel<<<1024, 256, 0, stream>>>(qb_, kb_, vt, attn);
  {
    dim3 g(8, 64);
    gemm_bt<<<g, 256, 0, stream>>>(attn, woutT, out, 8192, 1024, 1024);
  }
}

// Round 8
// 292.633 us; speedup vs baseline: 1.2570x; 1.2570x over previous
//
#include <hip/hip_runtime.h>
#include <hip/hip_bf16.h>
#include <math.h>

typedef __attribute__((ext_vector_type(8))) short bf16x8;
typedef __attribute__((ext_vector_type(4))) short short4v;
typedef __attribute__((ext_vector_type(4))) float f32x4;
typedef __attribute__((ext_vector_type(16))) float f32x16;

#define MFMA16(a,b,c) __builtin_amdgcn_mfma_f32_16x16x32_bf16(a,b,c,0,0,0)
#define MFMA32(a,b,c) __builtin_amdgcn_mfma_f32_32x32x16_bf16(a,b,c,0,0,0)

__device__ __forceinline__ unsigned short f2bf(float f) {
  union { float f; unsigned u; } v; v.f = f;
  unsigned r = v.u + 0x7FFFu + ((v.u >> 16) & 1u);
  return (unsigned short)(r >> 16);
}

__device__ __forceinline__ unsigned cvt_pk(float lo, float hi) {
  unsigned r;
  asm("v_cvt_pk_bf16_f32 %0, %1, %2" : "=v"(r) : "v"(lo), "v"(hi));
  return r;
}

__device__ __forceinline__ void async_load16(const void* g, void* lds) {
  __builtin_amdgcn_global_load_lds(
      (const __attribute__((address_space(1))) unsigned int*)g,
      (__attribute__((address_space(3))) unsigned int*)lds, 16, 0, 0);
}

__device__ __forceinline__ f32x16 zero16() {
  f32x16 z;
#pragma unroll
  for (int i = 0; i < 16; ++i) z[i] = 0.f;
  return z;
}

// ---------------- RoPE table ----------------
__global__ void rope_table_kernel(float* __restrict__ tc, float* __restrict__ ts) {
  int i = blockIdx.x * 256 + threadIdx.x;
  if (i >= 2048 * 32) return;
  int s = i >> 5, j = i & 31;
  double invf = pow(10000.0, -(double)(2 * j) / 64.0);
  double ang = (double)s * invf;
  tc[i] = (float)cos(ang);
  ts[i] = (float)sin(ang);
}

// ---------------- fp32 -> bf16 elementwise ----------------
__global__ __launch_bounds__(256) void cvt_kernel(const float* __restrict__ in,
                                                  unsigned short* __restrict__ out, int n4) {
  int i = blockIdx.x * 256 + threadIdx.x;
  if (i >= n4) return;
  float4 v = ((const float4*)in)[i];
  short4v o;
  o[0] = (short)f2bf(v.x); o[1] = (short)f2bf(v.y);
  o[2] = (short)f2bf(v.z); o[3] = (short)f2bf(v.w);
  *(short4v*)&out[(size_t)i * 4] = o;
}

// ---------------- fp32 [R][C] -> bf16 [C][R] transpose ----------------
__global__ __launch_bounds__(256) void transpose_cvt(const float* __restrict__ in,
                                                     unsigned short* __restrict__ out,
                                                     int R, int C) {
  __shared__ float tile[32][33];
  const int bx = blockIdx.x * 32, by = blockIdx.y * 32;
  const int tx = threadIdx.x & 31, ty0 = threadIdx.x >> 5;
#pragma unroll
  for (int p = 0; p < 4; ++p) {
    int r = ty0 + p * 8;
    tile[r][tx] = in[(size_t)(by + r) * C + bx + tx];
  }
  __syncthreads();
#pragma unroll
  for (int p = 0; p < 4; ++p) {
    int r = ty0 + p * 8;
    out[(size_t)(bx + r) * R + by + tx] = f2bf(tile[tx][r]);
  }
}

// ---------------- GEMM (m97 structure) ----------------
__global__ __launch_bounds__(256) void gemm_bt(const unsigned short* __restrict__ A,
                                               const unsigned short* __restrict__ Bt,
                                               float* __restrict__ C,
                                               int M, int N, int K) {
  __shared__ unsigned short As[128 * 32];
  __shared__ unsigned short Bs[128 * 32];
  const int t = threadIdx.x, lane = t & 63, wv = t >> 6;
  const int bn = blockIdx.x, bm = blockIdx.y;
  const int m0 = bm * 128, n0 = bn * 128;
  f32x4 acc[4][4];
#pragma unroll
  for (int m = 0; m < 4; ++m)
#pragma unroll
    for (int n = 0; n < 4; ++n) acc[m][n] = (f32x4){0.f, 0.f, 0.f, 0.f};
  const int wr = (wv >> 1) * 64, wc = (wv & 1) * 64;
  const int ar = lane & 15, ak = (lane >> 4) * 8;
  const int srow = lane >> 2, skc = (lane & 3) * 8;
  const int nkt = K >> 5;
  for (int kt = 0; kt < nkt; ++kt) {
    const unsigned short* Ag = A + (size_t)m0 * K + kt * 32;
    const unsigned short* Bg = Bt + (size_t)n0 * K + kt * 32;
#pragma unroll
    for (int p = 0; p < 2; ++p) {
      int c = wv * 2 + p;
      async_load16(Ag + (size_t)(c * 16 + srow) * K + skc, &As[c * 512]);
      async_load16(Bg + (size_t)(c * 16 + srow) * K + skc, &Bs[c * 512]);
    }
    __syncthreads();
    bf16x8 af[4], bfr[4];
#pragma unroll
    for (int m = 0; m < 4; ++m) af[m] = *(const bf16x8*)&As[(wr + m * 16 + ar) * 32 + ak];
#pragma unroll
    for (int n = 0; n < 4; ++n) bfr[n] = *(const bf16x8*)&Bs[(wc + n * 16 + ar) * 32 + ak];
#pragma unroll
    for (int m = 0; m < 4; ++m)
#pragma unroll
      for (int n = 0; n < 4; ++n) acc[m][n] = MFMA16(af[m], bfr[n], acc[m][n]);
    __syncthreads();
  }
#pragma unroll
  for (int m = 0; m < 4; ++m) {
    int row = m0 + wr + m * 16 + (lane >> 4) * 4;
#pragma unroll
    for (int n = 0; n < 4; ++n) {
      int col = n0 + wc + n * 16 + ar;
      float* cp = C + (size_t)row * N + col;
#pragma unroll
      for (int j = 0; j < 4; ++j) cp[(size_t)j * N] = acc[m][n][j];
    }
  }
}

// ---------------- RoPE apply + head split + V transpose ----------------
// Q gets 0.125 * log2(e) prescale (softmax runs in exp2 domain).
__global__ __launch_bounds__(256) void rope_kernel(const float* __restrict__ qkv,
                                                   const float* __restrict__ tc,
                                                   const float* __restrict__ ts,
                                                   unsigned short* __restrict__ qo,
                                                   unsigned short* __restrict__ ko,
                                                   unsigned short* __restrict__ vt) {
  const int S = 2048;
  const int bx = blockIdx.x;
  const int st = bx & 31, bh = bx >> 5;
  const int b = bh >> 4, h = bh & 15;
  const int t = threadIdx.x;
  const int sl = t >> 2, j0 = (t & 3) * 8;
  const int s = st * 64 + sl;
  const float* row = qkv + (size_t)(b * S + s) * 3072;
  float cv[8], sv[8];
#pragma unroll
  for (int i = 0; i < 8; ++i) {
    cv[i] = tc[s * 32 + j0 + i];
    sv[i] = ts[s * 32 + j0 + i];
  }
  __shared__ unsigned short vtile[64][66];
#pragma unroll
  for (int m = 0; m < 2; ++m) {
    const int col0 = m * 1024 + h * 64;
    const float qscale = (m == 0) ? 0.125f * 1.44269504088896340736f : 1.0f;
    float lo[8], hi[8];
#pragma unroll
    for (int i = 0; i < 8; ++i) {
      lo[i] = row[col0 + j0 + i];
      hi[i] = row[col0 + 32 + j0 + i];
    }
    bf16x8 outlo, outhi;
#pragma unroll
    for (int i = 0; i < 8; ++i) {
      outlo[i] = (short)f2bf((lo[i] * cv[i] - hi[i] * sv[i]) * qscale);
      outhi[i] = (short)f2bf((hi[i] * cv[i] + lo[i] * sv[i]) * qscale);
    }
    unsigned short* dst = (m == 0 ? qo : ko) + (size_t)(bh * S + s) * 64;
    *(bf16x8*)&dst[j0] = outlo;
    *(bf16x8*)&dst[32 + j0] = outhi;
  }
  {
    const int col0 = 2048 + h * 64;
#pragma unroll
    for (int i = 0; i < 8; ++i) {
      vtile[j0 + i][sl] = f2bf(row[col0 + j0 + i]);
      vtile[j0 + 32 + i][sl] = f2bf(row[col0 + 32 + j0 + i]);
    }
  }
  __syncthreads();
  {
    const int hd = t >> 2, sc0 = (t & 3) * 16;
    unsigned short* dst = vt + ((size_t)bh * 64 + hd) * S + st * 64 + sc0;
    bf16x8 a, bv;
#pragma unroll
    for (int i = 0; i < 8; ++i) {
      a[i] = (short)vtile[hd][sc0 + i];
      bv[i] = (short)vtile[hd][sc0 + 8 + i];
    }
    *(bf16x8*)&dst[0] = a;
    *(bf16x8*)&dst[8] = bv;
  }
}

// ---------------- attention: single-chain waves, KVBLK=32 ----------------
// One 32-row q-group per wave, 32-key tiles == R5's validated diag-even path
// (bank0-only QK, w[0..7], PV tt<2). 4096 waves -> 4 waves/SIMD TLP.
// Live state ~115 VGPR -> fits 128, no spill.

__device__ __forceinline__ bf16x8 buildP(const unsigned* w, int tt, int hi) {
  const int base = (tt & 1) * 4 + (tt >> 1) * 8;
  unsigned wA = w[base], wB = w[base + 1], wC = w[base + 2], wD = w[base + 3];
  unsigned s1v = __shfl_xor(hi ? wA : wC, 32);
  unsigned s2v = __shfl_xor(hi ? wB : wD, 32);
  union { unsigned u[4]; bf16x8 v; } pw;
  pw.u[0] = hi ? s1v : wA;
  pw.u[1] = hi ? s2v : wB;
  pw.u[2] = hi ? wC : s1v;
  pw.u[3] = hi ? wD : s2v;
  return pw.v;
}

// MASK: apply causal key>ql mask (final/diagonal tile only).
template<bool MASK>
__device__ __forceinline__ void tile32(
    const unsigned short* __restrict__ kb, const unsigned short* __restrict__ vb,
    int ql, int hi,
    const bf16x8 (&qf)[4], f32x16& a0, f32x16& a1, float& m_run, float& l_run) {
  const int S = 2048;
  bf16x8 k0[4];
#pragma unroll
  for (int s = 0; s < 4; ++s)
    k0[s] = *(const bf16x8*)&kb[ql * 64 + s * 16 + hi * 8];
  // V issued early; consumed after QK+softmax -> latency hidden
  bf16x8 v0[2], v1[2];
#pragma unroll
  for (int tt = 0; tt < 2; ++tt) {
    v0[tt] = *(const bf16x8*)&vb[(size_t)ql * S + tt * 16 + hi * 8];
    v1[tt] = *(const bf16x8*)&vb[(size_t)(32 + ql) * S + tt * 16 + hi * 8];
  }

  f32x16 s0 = zero16();
  __builtin_amdgcn_s_setprio(1);
#pragma unroll
  for (int s = 0; s < 4; ++s) s0 = MFMA32(k0[s], qf[s], s0);
  __builtin_amdgcn_s_setprio(0);

  if (MASK) {
#pragma unroll
    for (int r = 0; r < 16; ++r) {
      const int key = (r & 3) + 8 * (r >> 2) + 4 * hi;
      if (key > ql) s0[r] = -INFINITY;
    }
  }

  // softmax over 32 keys (16 regs + cross-half max)
  float p[8];
#pragma unroll
  for (int i = 0; i < 8; ++i) p[i] = fmaxf(s0[2 * i], s0[2 * i + 1]);
#pragma unroll
  for (int i = 0; i < 4; ++i) p[i] = fmaxf(p[i], p[i + 4]);
  float mx = fmaxf(fmaxf(p[0], p[1]), fmaxf(p[2], p[3]));
  mx = fmaxf(mx, __shfl_xor(mx, 32));
  const bool defer = __all(mx - m_run <= 8.0f) != 0;
  const float mn = defer ? m_run : fmaxf(m_run, mx);
  float r0 = 0.f, r1 = 0.f, r2 = 0.f, r3 = 0.f;
#pragma unroll
  for (int i = 0; i < 4; ++i) {
    float e0 = exp2f(s0[4 * i + 0] - mn); s0[4 * i + 0] = e0; r0 += e0;
    float e1 = exp2f(s0[4 * i + 1] - mn); s0[4 * i + 1] = e1; r1 += e1;
    float e2 = exp2f(s0[4 * i + 2] - mn); s0[4 * i + 2] = e2; r2 += e2;
    float e3 = exp2f(s0[4 * i + 3] - mn); s0[4 * i + 3] = e3; r3 += e3;
  }
  const float rs = (r0 + r1) + (r2 + r3);
  if (defer) {
    l_run += rs;
  } else {
    const float scl = exp2f(m_run - mn);
    m_run = mn;
    l_run = l_run * scl + rs;
#pragma unroll
    for (int r = 0; r < 16; ++r) { a0[r] *= scl; a1[r] *= scl; }
  }
  unsigned w[8];
#pragma unroll
  for (int i = 0; i < 8; ++i) w[i] = cvt_pk(s0[2 * i], s0[2 * i + 1]);

  __builtin_amdgcn_s_setprio(1);
#pragma unroll
  for (int tt = 0; tt < 2; ++tt) {
    bf16x8 pp = buildP(w, tt, hi);
    a0 = MFMA32(v0[tt], pp, a0);
    a1 = MFMA32(v1[tt], pp, a1);
  }
  __builtin_amdgcn_s_setprio(0);
}

// grid: 1024 blocks (XCD-swizzled: 8 chunks of 128). Block (bh, i): waves take
// groups {i, 31-i, 32+i, 63-i} rotated by (wv+i)&3 -> 130 tiles/block constant.
__global__ __launch_bounds__(256, 3) void attn_kernel(const unsigned short* __restrict__ Q,
                                                      const unsigned short* __restrict__ Kk,
                                                      const unsigned short* __restrict__ Vt,
                                                      unsigned short* __restrict__ O) {
  const int S = 2048;
  const int t = threadIdx.x, lane = t & 63, wv = t >> 6;
  const int swz = (blockIdx.x & 7) * 128 + (blockIdx.x >> 3);
  const int bh = swz >> 4, i = swz & 15;
  const int b = bh >> 4, h = bh & 15;
  const int sel = (wv + i) & 3;
  const int g = (sel == 0) ? i : (sel == 1) ? 31 - i : (sel == 2) ? 32 + i : 63 - i;
  const int ql = lane & 31, hi = lane >> 5;
  const unsigned short* qh = Q + (size_t)bh * S * 64;
  const unsigned short* kh = Kk + (size_t)bh * S * 64;
  const unsigned short* vh = Vt + (size_t)bh * 64 * S;

  bf16x8 qf[4];
#pragma unroll
  for (int s = 0; s < 4; ++s)
    qf[s] = *(const bf16x8*)&qh[(size_t)(32 * g + ql) * 64 + s * 16 + hi * 8];

  f32x16 a0 = zero16(), a1 = zero16();
  float m_run = -INFINITY, l_run = 0.f;

  for (int kt = 0; kt < g; ++kt)
    tile32<false>(kh + (size_t)kt * 2048, vh + kt * 32, ql, hi, qf, a0, a1, m_run, l_run);
  tile32<true>(kh + (size_t)g * 2048, vh + g * 32, ql, hi, qf, a0, a1, m_run, l_run);

  l_run += __shfl_xor(l_run, 32);
  const float inv = 1.f / l_run;
  unsigned short* orow = O + (size_t)(b * S + 32 * g + ql) * 1024 + h * 64;
#pragma unroll
  for (int r = 0; r < 16; ++r) {
    int d = (r & 3) + 8 * (r >> 2) + 4 * hi;
    orow[d] = f2bf(a0[r] * inv);
    orow[32 + d] = f2bf(a1[r] * inv);
  }
}

extern "C" void kernel_launch(void* const* d_in, const int* in_sizes, int n_in,
                              void* d_out, int out_size, void* d_ws, size_t ws_size,
                              hipStream_t stream) {
  const float* x = (const float*)d_in[0];
  const float* Wqkv = (const float*)d_in[1];
  const float* Wout = (const float*)d_in[2];
  float* out = (float*)d_out;

  char* ws = (char*)d_ws;
  size_t off = 0;
  auto take = [&](size_t bytes) {
    void* p = ws + off;
    off += (bytes + 255) & ~(size_t)255;
    return p;
  };
  float* tc = (float*)take(2048 * 32 * 4);
  float* tsn = (float*)take(2048 * 32 * 4);
  unsigned short* xbf = (unsigned short*)take((size_t)8192 * 1024 * 2);
  unsigned short* wqkvT = (unsigned short*)take((size_t)3072 * 1024 * 2);
  unsigned short* woutT = (unsigned short*)take((size_t)1024 * 1024 * 2);
  float* qkvf = (float*)take((size_t)8192 * 3072 * 4);
  unsigned short* qb_ = (unsigned short*)take((size_t)64 * 2048 * 64 * 2);
  unsigned short* kb_ = (unsigned short*)take((size_t)64 * 2048 * 64 * 2);
  unsigned short* vt = (unsigned short*)take((size_t)64 * 64 * 2048 * 2);
  unsigned short* attn = (unsigned short*)take((size_t)8192 * 1024 * 2);

  rope_table_kernel<<<256, 256, 0, stream>>>(tc, tsn);
  cvt_kernel<<<(2097152 + 255) / 256, 256, 0, stream>>>(x, xbf, 2097152);
  {
    dim3 g(96, 32);
    transpose_cvt<<<g, 256, 0, stream>>>(Wqkv, wqkvT, 1024, 3072);
  }
  {
    dim3 g(32, 32);
    transpose_cvt<<<g, 256, 0, stream>>>(Wout, woutT, 1024, 1024);
  }
  {
    dim3 g(24, 64);
    gemm_bt<<<g, 256, 0, stream>>>(xbf, wqkvT, qkvf, 8192, 3072, 1024);
  }
  rope_kernel<<<2048, 256, 0, stream>>>(qkvf, tc, tsn, qb_, kb_, vt);
  attn_kernel<<<1024, 256, 0, stream>>>(qb_, kb_, vt, attn);
  {
    dim3 g(8, 64);
    gemm_bt<<<g, 256, 0, stream>>>(attn, woutT, out, 8192, 1024, 1024);
  }
}

// Round 9
// 266.233 us; speedup vs baseline: 1.3817x; 1.0992x over previous
//
#include <hip/hip_runtime.h>
#include <hip/hip_bf16.h>
#include <math.h>

typedef __attribute__((ext_vector_type(8))) short bf16x8;
typedef __attribute__((ext_vector_type(4))) short short4v;
typedef __attribute__((ext_vector_type(4))) float f32x4;
typedef __attribute__((ext_vector_type(16))) float f32x16;

#define MFMA16(a,b,c) __builtin_amdgcn_mfma_f32_16x16x32_bf16(a,b,c,0,0,0)
#define MFMA32(a,b,c) __builtin_amdgcn_mfma_f32_32x32x16_bf16(a,b,c,0,0,0)

__device__ __forceinline__ unsigned short f2bf(float f) {
  union { float f; unsigned u; } v; v.f = f;
  unsigned r = v.u + 0x7FFFu + ((v.u >> 16) & 1u);
  return (unsigned short)(r >> 16);
}
__device__ __forceinline__ float b2f(unsigned short u) {
  union { unsigned u; float f; } v; v.u = (unsigned)u << 16; return v.f;
}

__device__ __forceinline__ unsigned cvt_pk(float lo, float hi) {
  unsigned r;
  asm("v_cvt_pk_bf16_f32 %0, %1, %2" : "=v"(r) : "v"(lo), "v"(hi));
  return r;
}
__device__ __forceinline__ float fexp2(float x) {
  float r;
  asm("v_exp_f32 %0, %1" : "=v"(r) : "v"(x));
  return r;
}

__device__ __forceinline__ void async_load16(const void* g, void* lds) {
  __builtin_amdgcn_global_load_lds(
      (const __attribute__((address_space(1))) unsigned int*)g,
      (__attribute__((address_space(3))) unsigned int*)lds, 16, 0, 0);
}

__device__ __forceinline__ f32x16 zero16() {
  f32x16 z;
#pragma unroll
  for (int i = 0; i < 16; ++i) z[i] = 0.f;
  return z;
}

// ---------------- RoPE table ----------------
__global__ void rope_table_kernel(float* __restrict__ tc, float* __restrict__ ts) {
  int i = blockIdx.x * 256 + threadIdx.x;
  if (i >= 2048 * 32) return;
  int s = i >> 5, j = i & 31;
  double invf = pow(10000.0, -(double)(2 * j) / 64.0);
  double ang = (double)s * invf;
  tc[i] = (float)cos(ang);
  ts[i] = (float)sin(ang);
}

// ---------------- fp32 -> bf16 elementwise ----------------
__global__ __launch_bounds__(256) void cvt_kernel(const float* __restrict__ in,
                                                  unsigned short* __restrict__ out, int n4) {
  int i = blockIdx.x * 256 + threadIdx.x;
  if (i >= n4) return;
  float4 v = ((const float4*)in)[i];
  short4v o;
  o[0] = (short)f2bf(v.x); o[1] = (short)f2bf(v.y);
  o[2] = (short)f2bf(v.z); o[3] = (short)f2bf(v.w);
  *(short4v*)&out[(size_t)i * 4] = o;
}

// ---------------- fp32 [R][C] -> bf16 [C][R] transpose ----------------
__global__ __launch_bounds__(256) void transpose_cvt(const float* __restrict__ in,
                                                     unsigned short* __restrict__ out,
                                                     int R, int C) {
  __shared__ float tile[32][33];
  const int bx = blockIdx.x * 32, by = blockIdx.y * 32;
  const int tx = threadIdx.x & 31, ty0 = threadIdx.x >> 5;
#pragma unroll
  for (int p = 0; p < 4; ++p) {
    int r = ty0 + p * 8;
    tile[r][tx] = in[(size_t)(by + r) * C + bx + tx];
  }
  __syncthreads();
#pragma unroll
  for (int p = 0; p < 4; ++p) {
    int r = ty0 + p * 8;
    out[(size_t)(bx + r) * R + by + tx] = f2bf(tile[tx][r]);
  }
}

// ---------------- GEMM (m97 structure); BF16OUT selects output dtype ----------
template<bool BF16OUT>
__global__ __launch_bounds__(256) void gemm_bt(const unsigned short* __restrict__ A,
                                               const unsigned short* __restrict__ Bt,
                                               void* __restrict__ Cv,
                                               int M, int N, int K) {
  __shared__ unsigned short As[128 * 32];
  __shared__ unsigned short Bs[128 * 32];
  const int t = threadIdx.x, lane = t & 63, wv = t >> 6;
  const int bn = blockIdx.x, bm = blockIdx.y;
  const int m0 = bm * 128, n0 = bn * 128;
  f32x4 acc[4][4];
#pragma unroll
  for (int m = 0; m < 4; ++m)
#pragma unroll
    for (int n = 0; n < 4; ++n) acc[m][n] = (f32x4){0.f, 0.f, 0.f, 0.f};
  const int wr = (wv >> 1) * 64, wc = (wv & 1) * 64;
  const int ar = lane & 15, ak = (lane >> 4) * 8;
  const int srow = lane >> 2, skc = (lane & 3) * 8;
  const int nkt = K >> 5;
  for (int kt = 0; kt < nkt; ++kt) {
    const unsigned short* Ag = A + (size_t)m0 * K + kt * 32;
    const unsigned short* Bg = Bt + (size_t)n0 * K + kt * 32;
#pragma unroll
    for (int p = 0; p < 2; ++p) {
      int c = wv * 2 + p;
      async_load16(Ag + (size_t)(c * 16 + srow) * K + skc, &As[c * 512]);
      async_load16(Bg + (size_t)(c * 16 + srow) * K + skc, &Bs[c * 512]);
    }
    __syncthreads();
    bf16x8 af[4], bfr[4];
#pragma unroll
    for (int m = 0; m < 4; ++m) af[m] = *(const bf16x8*)&As[(wr + m * 16 + ar) * 32 + ak];
#pragma unroll
    for (int n = 0; n < 4; ++n) bfr[n] = *(const bf16x8*)&Bs[(wc + n * 16 + ar) * 32 + ak];
#pragma unroll
    for (int m = 0; m < 4; ++m)
#pragma unroll
      for (int n = 0; n < 4; ++n) acc[m][n] = MFMA16(af[m], bfr[n], acc[m][n]);
    __syncthreads();
  }
#pragma unroll
  for (int m = 0; m < 4; ++m) {
    int row = m0 + wr + m * 16 + (lane >> 4) * 4;
#pragma unroll
    for (int n = 0; n < 4; ++n) {
      int col = n0 + wc + n * 16 + ar;
      if (BF16OUT) {
        unsigned short* cp = (unsigned short*)Cv + (size_t)row * N + col;
#pragma unroll
        for (int j = 0; j < 4; ++j) cp[(size_t)j * N] = f2bf(acc[m][n][j]);
      } else {
        float* cp = (float*)Cv + (size_t)row * N + col;
#pragma unroll
        for (int j = 0; j < 4; ++j) cp[(size_t)j * N] = acc[m][n][j];
      }
    }
  }
}

// ---------------- RoPE apply + head split + V transpose (bf16 qkv in) -------
// Q gets 0.125 * log2(e) prescale (softmax runs in exp2 domain).
__global__ __launch_bounds__(256) void rope_kernel(const unsigned short* __restrict__ qkv,
                                                   const float* __restrict__ tc,
                                                   const float* __restrict__ ts,
                                                   unsigned short* __restrict__ qo,
                                                   unsigned short* __restrict__ ko,
                                                   unsigned short* __restrict__ vt) {
  const int S = 2048;
  const int bx = blockIdx.x;
  const int st = bx & 31, bh = bx >> 5;
  const int b = bh >> 4, h = bh & 15;
  const int t = threadIdx.x;
  const int sl = t >> 2, j0 = (t & 3) * 8;
  const int s = st * 64 + sl;
  const unsigned short* row = qkv + (size_t)(b * S + s) * 3072;
  float cv[8], sv[8];
#pragma unroll
  for (int i = 0; i < 8; ++i) {
    cv[i] = tc[s * 32 + j0 + i];
    sv[i] = ts[s * 32 + j0 + i];
  }
  __shared__ unsigned short vtile[64][66];
#pragma unroll
  for (int m = 0; m < 2; ++m) {
    const int col0 = m * 1024 + h * 64;
    const float qscale = (m == 0) ? 0.125f * 1.44269504088896340736f : 1.0f;
    bf16x8 lo8 = *(const bf16x8*)&row[col0 + j0];
    bf16x8 hi8 = *(const bf16x8*)&row[col0 + 32 + j0];
    bf16x8 outlo, outhi;
#pragma unroll
    for (int i = 0; i < 8; ++i) {
      float lo = b2f((unsigned short)lo8[i]), hi = b2f((unsigned short)hi8[i]);
      outlo[i] = (short)f2bf((lo * cv[i] - hi * sv[i]) * qscale);
      outhi[i] = (short)f2bf((hi * cv[i] + lo * sv[i]) * qscale);
    }
    unsigned short* dst = (m == 0 ? qo : ko) + (size_t)(bh * S + s) * 64;
    *(bf16x8*)&dst[j0] = outlo;
    *(bf16x8*)&dst[32 + j0] = outhi;
  }
  {
    const int col0 = 2048 + h * 64;
    bf16x8 v8a = *(const bf16x8*)&row[col0 + j0];
    bf16x8 v8b = *(const bf16x8*)&row[col0 + 32 + j0];
#pragma unroll
    for (int i = 0; i < 8; ++i) {
      vtile[j0 + i][sl] = (unsigned short)v8a[i];
      vtile[j0 + 32 + i][sl] = (unsigned short)v8b[i];
    }
  }
  __syncthreads();
  {
    const int hd = t >> 2, sc0 = (t & 3) * 16;
    unsigned short* dst = vt + ((size_t)bh * 64 + hd) * S + st * 64 + sc0;
    bf16x8 a, bv;
#pragma unroll
    for (int i = 0; i < 8; ++i) {
      a[i] = (short)vtile[hd][sc0 + i];
      bv[i] = (short)vtile[hd][sc0 + 8 + i];
    }
    *(bf16x8*)&dst[0] = a;
    *(bf16x8*)&dst[8] = bv;
  }
}

// ---------------- attention: KVBLK=32 single chain + K prefetch ----------------
// R8 math; hoisted per-lane pointers (imm offsets per tile) and 1-deep K
// register prefetch to hide head-of-chain load latency.

__device__ __forceinline__ bf16x8 buildP(const unsigned* w, int tt, int hi) {
  const int base = (tt & 1) * 4 + (tt >> 1) * 8;
  unsigned wA = w[base], wB = w[base + 1], wC = w[base + 2], wD = w[base + 3];
  unsigned s1v = __shfl_xor(hi ? wA : wC, 32);
  unsigned s2v = __shfl_xor(hi ? wB : wD, 32);
  union { unsigned u[4]; bf16x8 v; } pw;
  pw.u[0] = hi ? s1v : wA;
  pw.u[1] = hi ? s2v : wB;
  pw.u[2] = hi ? wC : s1v;
  pw.u[3] = hi ? wD : s2v;
  return pw.v;
}

template<bool MASK>
__device__ __forceinline__ void tile32(
    const bf16x8 (&k0)[4],
    const unsigned short* __restrict__ vrow0, const unsigned short* __restrict__ vrow1,
    int ql, int hi,
    const bf16x8 (&qf)[4], f32x16& a0, f32x16& a1, float& m_run, float& l_run) {
  // V issued first; consumed after QK+softmax -> latency hidden
  bf16x8 v0[2], v1[2];
  v0[0] = *(const bf16x8*)&vrow0[0];
  v0[1] = *(const bf16x8*)&vrow0[16];
  v1[0] = *(const bf16x8*)&vrow1[0];
  v1[1] = *(const bf16x8*)&vrow1[16];

  f32x16 s0 = zero16();
  __builtin_amdgcn_s_setprio(1);
#pragma unroll
  for (int s = 0; s < 4; ++s) s0 = MFMA32(k0[s], qf[s], s0);
  __builtin_amdgcn_s_setprio(0);

  if (MASK) {
#pragma unroll
    for (int r = 0; r < 16; ++r) {
      const int key = (r & 3) + 8 * (r >> 2) + 4 * hi;
      if (key > ql) s0[r] = -INFINITY;
    }
  }

  float p[8];
#pragma unroll
  for (int i = 0; i < 8; ++i) p[i] = fmaxf(s0[2 * i], s0[2 * i + 1]);
#pragma unroll
  for (int i = 0; i < 4; ++i) p[i] = fmaxf(p[i], p[i + 4]);
  float mx = fmaxf(fmaxf(p[0], p[1]), fmaxf(p[2], p[3]));
  mx = fmaxf(mx, __shfl_xor(mx, 32));
  const bool defer = __all(mx - m_run <= 8.0f) != 0;
  const float mn = defer ? m_run : fmaxf(m_run, mx);
  float r0 = 0.f, r1 = 0.f, r2 = 0.f, r3 = 0.f;
#pragma unroll
  for (int i = 0; i < 4; ++i) {
    float e0 = fexp2(s0[4 * i + 0] - mn); s0[4 * i + 0] = e0; r0 += e0;
    float e1 = fexp2(s0[4 * i + 1] - mn); s0[4 * i + 1] = e1; r1 += e1;
    float e2 = fexp2(s0[4 * i + 2] - mn); s0[4 * i + 2] = e2; r2 += e2;
    float e3 = fexp2(s0[4 * i + 3] - mn); s0[4 * i + 3] = e3; r3 += e3;
  }
  const float rs = (r0 + r1) + (r2 + r3);
  if (defer) {
    l_run += rs;
  } else {
    const float scl = fexp2(m_run - mn);
    m_run = mn;
    l_run = l_run * scl + rs;
#pragma unroll
    for (int r = 0; r < 16; ++r) { a0[r] *= scl; a1[r] *= scl; }
  }
  unsigned w[8];
#pragma unroll
  for (int i = 0; i < 8; ++i) w[i] = cvt_pk(s0[2 * i], s0[2 * i + 1]);

  __builtin_amdgcn_s_setprio(1);
#pragma unroll
  for (int tt = 0; tt < 2; ++tt) {
    bf16x8 pp = buildP(w, tt, hi);
    a0 = MFMA32(v0[tt], pp, a0);
    a1 = MFMA32(v1[tt], pp, a1);
  }
  __builtin_amdgcn_s_setprio(0);
}

// grid: 1024 blocks (XCD-swizzled). Block (bh, i): waves take groups
// {i, 31-i, 32+i, 63-i} rotated by (wv+i)&3 -> 130 tiles/block constant.
__global__ __launch_bounds__(256, 3) void attn_kernel(const unsigned short* __restrict__ Q,
                                                      const unsigned short* __restrict__ Kk,
                                                      const unsigned short* __restrict__ Vt,
                                                      unsigned short* __restrict__ O) {
  const int S = 2048;
  const int t = threadIdx.x, lane = t & 63, wv = t >> 6;
  const int swz = (blockIdx.x & 7) * 128 + (blockIdx.x >> 3);
  const int bh = swz >> 4, i = swz & 15;
  const int b = bh >> 4, h = bh & 15;
  const int sel = (wv + i) & 3;
  const int g = (sel == 0) ? i : (sel == 1) ? 31 - i : (sel == 2) ? 32 + i : 63 - i;
  const int ql = lane & 31, hi = lane >> 5;
  const unsigned short* qh = Q + (size_t)bh * S * 64;
  const unsigned short* kh = Kk + (size_t)bh * S * 64;
  const unsigned short* vh = Vt + (size_t)bh * 64 * S;

  bf16x8 qf[4];
#pragma unroll
  for (int s = 0; s < 4; ++s)
    qf[s] = *(const bf16x8*)&qh[(size_t)(32 * g + ql) * 64 + s * 16 + hi * 8];

  f32x16 a0 = zero16(), a1 = zero16();
  float m_run = -INFINITY, l_run = 0.f;

  // hoisted per-lane pointers: per tile, krow += 2048 elems, vrow += 32 elems.
  const unsigned short* krow = kh + ql * 64 + hi * 8;
  const unsigned short* vrow0 = vh + (size_t)ql * S + hi * 8;
  const unsigned short* vrow1 = vh + (size_t)(32 + ql) * S + hi * 8;

  bf16x8 kcur[4];
#pragma unroll
  for (int s = 0; s < 4; ++s) kcur[s] = *(const bf16x8*)&krow[s * 16];

  for (int kt = 0; kt < g; ++kt) {
    krow += 2048;
    bf16x8 knext[4];
#pragma unroll
    for (int s = 0; s < 4; ++s) knext[s] = *(const bf16x8*)&krow[s * 16];
    tile32<false>(kcur, vrow0, vrow1, ql, hi, qf, a0, a1, m_run, l_run);
    vrow0 += 32;
    vrow1 += 32;
#pragma unroll
    for (int s = 0; s < 4; ++s) kcur[s] = knext[s];
  }
  tile32<true>(kcur, vrow0, vrow1, ql, hi, qf, a0, a1, m_run, l_run);

  l_run += __shfl_xor(l_run, 32);
  const float inv = 1.f / l_run;
  unsigned short* orow = O + (size_t)(b * S + 32 * g + ql) * 1024 + h * 64;
#pragma unroll
  for (int r = 0; r < 16; ++r) {
    int d = (r & 3) + 8 * (r >> 2) + 4 * hi;
    orow[d] = f2bf(a0[r] * inv);
    orow[32 + d] = f2bf(a1[r] * inv);
  }
}

extern "C" void kernel_launch(void* const* d_in, const int* in_sizes, int n_in,
                              void* d_out, int out_size, void* d_ws, size_t ws_size,
                              hipStream_t stream) {
  const float* x = (const float*)d_in[0];
  const float* Wqkv = (const float*)d_in[1];
  const float* Wout = (const float*)d_in[2];
  float* out = (float*)d_out;

  char* ws = (char*)d_ws;
  size_t off = 0;
  auto take = [&](size_t bytes) {
    void* p = ws + off;
    off += (bytes + 255) & ~(size_t)255;
    return p;
  };
  float* tc = (float*)take(2048 * 32 * 4);
  float* tsn = (float*)take(2048 * 32 * 4);
  unsigned short* xbf = (unsigned short*)take((size_t)8192 * 1024 * 2);
  unsigned short* wqkvT = (unsigned short*)take((size_t)3072 * 1024 * 2);
  unsigned short* woutT = (unsigned short*)take((size_t)1024 * 1024 * 2);
  unsigned short* qkvb = (unsigned short*)take((size_t)8192 * 3072 * 2);
  unsigned short* qb_ = (unsigned short*)take((size_t)64 * 2048 * 64 * 2);
  unsigned short* kb_ = (unsigned short*)take((size_t)64 * 2048 * 64 * 2);
  unsigned short* vt = (unsigned short*)take((size_t)64 * 64 * 2048 * 2);
  unsigned short* attn = (unsigned short*)take((size_t)8192 * 1024 * 2);

  rope_table_kernel<<<256, 256, 0, stream>>>(tc, tsn);
  cvt_kernel<<<(2097152 + 255) / 256, 256, 0, stream>>>(x, xbf, 2097152);
  {
    dim3 g(96, 32);
    transpose_cvt<<<g, 256, 0, stream>>>(Wqkv, wqkvT, 1024, 3072);
  }
  {
    dim3 g(32, 32);
    transpose_cvt<<<g, 256, 0, stream>>>(Wout, woutT, 1024, 1024);
  }
  {
    dim3 g(24, 64);
    gemm_bt<true><<<g, 256, 0, stream>>>(xbf, wqkvT, qkvb, 8192, 3072, 1024);
  }
  rope_kernel<<<2048, 256, 0, stream>>>(qkvb, tc, tsn, qb_, kb_, vt);
  attn_kernel<<<1024, 256, 0, stream>>>(qb_, kb_, vt, attn);
  {
    dim3 g(8, 64);
    gemm_bt<false><<<g, 256, 0, stream>>>(attn, woutT, out, 8192, 1024, 1024);
  }
}